// Round 10
// baseline (209.564 us; speedup 1.0000x reference)
//
#include <hip/hip_runtime.h>
#include <stdint.h>

// ---------- types ----------
typedef __bf16 bf16x8 __attribute__((ext_vector_type(8)));
typedef float f32x4 __attribute__((ext_vector_type(4)));
typedef unsigned short u16x4 __attribute__((ext_vector_type(4)));

static __device__ __forceinline__ unsigned short f2bf(float f) {
    union { float f; unsigned u; } v; v.f = f;
    unsigned r = (v.u + 0x7FFFu + ((v.u >> 16) & 1u)) >> 16;  // RNE
    return (unsigned short)r;
}

// ---------- fused prep: convert X, convert adj, transpose W0/W1/W2 ----------
__global__ void prep_kernel(const float* __restrict__ X,
                            const float* __restrict__ adj,
                            const float* __restrict__ W0,
                            const float* __restrict__ W1,
                            const float* __restrict__ W2,
                            unsigned short* __restrict__ bufH,
                            unsigned short* __restrict__ adjB,
                            unsigned short* __restrict__ Wt) {
    const int bid = blockIdx.x;
    const int t = threadIdx.x;
    if (bid < 16384) {
        const float* src = (bid < 8192) ? X : adj;
        unsigned short* dst = (bid < 8192) ? bufH : adjB;
        const int i = (bid & 8191) * 256 + t;
        f32x4 v = ((const f32x4*)src)[i];
        u16x4 o;
        o.x = f2bf(v.x); o.y = f2bf(v.y); o.z = f2bf(v.z); o.w = f2bf(v.w);
        ((u16x4*)dst)[i] = o;
    } else {
        const int wb = bid - 16384;          // 0..767
        const int z = wb >> 8;               // which W
        const int tile = wb & 255;           // 16x16 tiles of 32x32
        const float* W = (z == 0) ? W0 : (z == 1) ? W1 : W2;
        unsigned short* out = Wt + (size_t)z * (512 * 512);
        __shared__ float tileS[32][33];
        const int bx = (tile & 15) * 32, by = (tile >> 4) * 32;
        const int tx = t & 31, ty = t >> 5;  // 32 x 8
        #pragma unroll
        for (int r = 0; r < 32; r += 8)
            tileS[ty + r][tx] = W[(size_t)(by + ty + r) * 512 + (bx + tx)];
        __syncthreads();
        #pragma unroll
        for (int r = 0; r < 32; r += 8)
            out[(size_t)(bx + ty + r) * 512 + (by + tx)] = f2bf(tileS[tx][ty + r]);
    }
}

// ---------- GEMM: D[m][n] = sum_k A[m*LDA+k]*B[n*LDB+k]; writes out[n*LDO+m]
// 128x128 tile, XCD-affinity decode + coalesced LDS-transpose epilogue
// (unchanged from round 5).
// NEW this round: m201-style PHASE PIPELINE. Ring of 4 BK=32 buffers
// (same 64 KB LDS, 2 blocks/CU). 16 phases; each phase:
//   s_waitcnt vmcnt(8)   // own stage-h loads landed; h+1,h+2 still flying
//   s_barrier            // ONE barrier/phase: stage-h visible to all waves
//                        // AND all waves' phase h-1 reads are complete
//   STAGE(h+3)           // 4 gload_lds into the buffer freed in phase h-1
//   ds_read x8 + 16 MFMA (setprio-wrapped; compiler-managed lgkmcnt)
// Stage issue leads its wait by 3 phases; vmcnt never drains in the main
// loop (T3+T4 proper; R3's coarse counted-vmcnt lacked this interleave).
// LDS per buffer: 128 rows x 4 chunks(16B), swizzle chunk(row,pos) at
// row*4 + (pos ^ (row&3)); staging thread t: row=t>>2, pos=(t&3)^((t>>2)&3).
template<int LDA, int LDB, int LDO, bool BIAS, bool RELU, bool ADJ, typename OT>
__global__ __launch_bounds__(256, 2)
void gemm_abT_ct(const unsigned short* __restrict__ A,
                 const unsigned short* __restrict__ B,
                 OT* __restrict__ out, const float* __restrict__ bias,
                 long batchA, long batchB, long batchO) {
    __shared__ char SMEM[65536];   // A ring: 4 x 8KB at 0; B ring: 4 x 8KB at 32768

    const int tid  = threadIdx.x;
    const int lane = tid & 63;
    const int wave = tid >> 6;
    const int quad = lane >> 4;
    const int l16  = lane & 15;
    const int wm   = wave & 1;
    const int wn   = wave >> 1;

    // ---- XCD-affinity decode (round 4/5 version; bijective over 512) ----
    const int L = blockIdx.x;
    const int x = L & 7;        // XCD id (hw round-robin on linear block id)
    const int j = L >> 3;       // 0..63 within XCD
    int m0, n0;
    long z;
    if constexpr (ADJ) {
        z = x + 8 * (j >> 4);             // 4 z's per XCD
        const int t4 = j & 15;            // 16 tiles of this z
        m0 = (t4 & 3) * 128;
        n0 = (t4 >> 2) * 128;
    } else {
        z = 0;
        m0 = (x * 16 + (j >> 2)) * 128;   // XCD x owns 16 consecutive m-tiles
        n0 = (j & 3) * 128;
    }
    A   += (size_t)z * batchA;
    B   += (size_t)z * batchB;
    out += (size_t)z * batchO;

    const int trow4 = tid >> 2;                   // 0..63
    const int tpos4 = (tid & 3) ^ (trow4 & 3);    // r-independent swizzled pos
    const unsigned short* aG = A + (size_t)(m0 + trow4) * LDA + tpos4 * 8;
    const unsigned short* bG = B + (size_t)(n0 + trow4) * LDB + tpos4 * 8;

    f32x4 acc[4][4];
    #pragma unroll
    for (int i = 0; i < 4; ++i)
        #pragma unroll
        for (int j2 = 0; j2 < 4; ++j2) {
            f32x4 zz = {0.f, 0.f, 0.f, 0.f};
            acc[i][j2] = zz;
        }

// issue 4 global_load_lds (2 A rounds + 2 B rounds) into ring slot `buf`
#define STAGE(buf, ko)                                                         \
    do {                                                                       \
        char* aL = SMEM + (buf) * 8192 + tid * 16;                             \
        char* bL = SMEM + 32768 + (buf) * 8192 + tid * 16;                     \
        _Pragma("unroll")                                                      \
        for (int r = 0; r < 2; ++r)                                            \
            __builtin_amdgcn_global_load_lds(                                  \
                (__attribute__((address_space(1))) void*)(uintptr_t)(aG + (size_t)(r * 64) * LDA + (ko)), \
                (__attribute__((address_space(3))) void*)(aL + r * 4096), 16, 0, 0); \
        _Pragma("unroll")                                                      \
        for (int r = 0; r < 2; ++r)                                            \
            __builtin_amdgcn_global_load_lds(                                  \
                (__attribute__((address_space(1))) void*)(uintptr_t)(bG + (size_t)(r * 64) * LDB + (ko)), \
                (__attribute__((address_space(3))) void*)(bL + r * 4096), 16, 0, 0); \
    } while (0)

// one BK=32 phase body: 4+4 ds_read_b128 + 16 MFMA on ring slot `buf`
// (compiler-managed lgkmcnt between reads and MFMAs; all reads are consumed
// by this phase's MFMAs, so they complete before the wave reaches the next
// phase's barrier -- which is the buffer-reuse invariant)
#define COMPUTE(buf)                                                           \
    do {                                                                       \
        const char* Ab = SMEM + (buf) * 8192;                                  \
        const char* Bb = SMEM + 32768 + (buf) * 8192;                          \
        bf16x8 af[4], bfr[4];                                                  \
        _Pragma("unroll")                                                      \
        for (int i = 0; i < 4; ++i) {                                          \
            const int row = wm * 64 + i * 16 + l16;                            \
            const int idx = row * 4 + (quad ^ (row & 3));                      \
            af[i] = *(const bf16x8*)(Ab + idx * 16);                           \
        }                                                                      \
        _Pragma("unroll")                                                      \
        for (int j2 = 0; j2 < 4; ++j2) {                                       \
            const int row = wn * 64 + j2 * 16 + l16;                           \
            const int idx = row * 4 + (quad ^ (row & 3));                      \
            bfr[j2] = *(const bf16x8*)(Bb + idx * 16);                         \
        }                                                                      \
        __builtin_amdgcn_s_setprio(1);                                         \
        _Pragma("unroll")                                                      \
        for (int i = 0; i < 4; ++i)                                            \
            _Pragma("unroll")                                                  \
            for (int j2 = 0; j2 < 4; ++j2)                                     \
                acc[i][j2] = __builtin_amdgcn_mfma_f32_16x16x32_bf16(af[i], bfr[j2], acc[i][j2], 0, 0, 0); \
        __builtin_amdgcn_s_setprio(0);                                         \
    } while (0)

    STAGE(0, 0);
    STAGE(1, 32);
    STAGE(2, 64);     // 12 loads/thread in flight

    #pragma unroll 1
    for (int h = 0; h < 13; ++h) {         // phases 0..12, prefetch h+3
        asm volatile("s_waitcnt vmcnt(8)" ::: "memory");   // stage h landed
        __builtin_amdgcn_s_barrier();                      // one barrier/phase
        STAGE((h + 3) & 3, (h + 3) * 32);                  // refill freed slot
        COMPUTE(h & 3);
    }
    // tail: phases 13,14,15 (no more stages; drain 8 -> 4 -> 0)
    asm volatile("s_waitcnt vmcnt(8)" ::: "memory");
    __builtin_amdgcn_s_barrier();
    COMPUTE(1);
    asm volatile("s_waitcnt vmcnt(4)" ::: "memory");
    __builtin_amdgcn_s_barrier();
    COMPUTE(2);
    asm volatile("s_waitcnt vmcnt(0)" ::: "memory");
    __builtin_amdgcn_s_barrier();
    COMPUTE(3);
#undef STAGE
#undef COMPUTE

    __syncthreads();   // all waves' reads done; SMEM reusable for epilogue

    // ---- coalesced epilogue via LDS transpose (unchanged from round 5) ----
    if constexpr (sizeof(OT) == 2) {
        // bf16 tile [n=128][m=128], 256B rows = 16 x 16B chunks, chunk ^= n&7
        unsigned short* T = (unsigned short*)SMEM;   // 32 KB
        #pragma unroll
        for (int i = 0; i < 4; ++i) {
            const int mloc = wm * 64 + i * 16 + quad * 4;
            const int mb = m0 + mloc;
            f32x4 bb = {0.f, 0.f, 0.f, 0.f};
            if constexpr (BIAS) bb = *(const f32x4*)(bias + mb);
            const int ch  = mloc >> 3;           // 16B chunk index 0..15
            const int sub = (mloc & 7) * 2;      // byte offset within chunk
            #pragma unroll
            for (int j2 = 0; j2 < 4; ++j2) {
                const int nloc = wn * 64 + j2 * 16 + l16;
                f32x4 v = acc[i][j2];
                if constexpr (BIAS) v += bb;
                if constexpr (RELU) {
                    v.x = v.x > 0.f ? v.x : 0.f;
                    v.y = v.y > 0.f ? v.y : 0.f;
                    v.z = v.z > 0.f ? v.z : 0.f;
                    v.w = v.w > 0.f ? v.w : 0.f;
                }
                u16x4 o;
                o.x = f2bf(v.x); o.y = f2bf(v.y); o.z = f2bf(v.z); o.w = f2bf(v.w);
                *(u16x4*)((char*)T + nloc * 256 + ((ch ^ (nloc & 7)) << 4) + sub) = o;
            }
        }
        __syncthreads();
        #pragma unroll
        for (int it = 0; it < 8; ++it) {
            const int n  = (tid >> 4) + 16 * it;   // 0..127
            const int cc = tid & 15;               // 16 lanes = 256B dense row
            f32x4 d = *(const f32x4*)((const char*)T + n * 256 + ((cc ^ (n & 7)) << 4));
            *(f32x4*)((unsigned short*)out + (size_t)(n0 + n) * LDO + m0 + cc * 8) = d;
        }
    } else {
        // f32 tile [n=128][m=128], 512B rows = 32 x 16B chunks, chunk ^= n&7 (64 KB)
        float* T = (float*)SMEM;
        #pragma unroll
        for (int i = 0; i < 4; ++i) {
            const int mloc = wm * 64 + i * 16 + quad * 4;
            const int mb = m0 + mloc;
            f32x4 bb = {0.f, 0.f, 0.f, 0.f};
            if constexpr (BIAS) bb = *(const f32x4*)(bias + mb);
            const int ch = mloc >> 2;            // 16B chunk index 0..31
            #pragma unroll
            for (int j2 = 0; j2 < 4; ++j2) {
                const int nloc = wn * 64 + j2 * 16 + l16;
                f32x4 v = acc[i][j2];
                if constexpr (BIAS) v += bb;
                if constexpr (RELU) {
                    v.x = v.x > 0.f ? v.x : 0.f;
                    v.y = v.y > 0.f ? v.y : 0.f;
                    v.z = v.z > 0.f ? v.z : 0.f;
                    v.w = v.w > 0.f ? v.w : 0.f;
                }
                *(f32x4*)((char*)T + nloc * 512 + ((ch ^ (nloc & 7)) << 4)) = v;
            }
        }
        __syncthreads();
        #pragma unroll
        for (int it = 0; it < 16; ++it) {
            const int n  = (tid >> 4) + 16 * (it >> 1);      // 0..127
            const int cc = (tid & 15) + 16 * (it & 1);       // 0..31
            f32x4 d = *(const f32x4*)((const char*)T + n * 512 + ((cc ^ (n & 7)) << 4));
            *(f32x4*)((float*)out + (size_t)(n0 + n) * LDO + m0 + cc * 4) = d;
        }
    }
}

extern "C" void kernel_launch(void* const* d_in, const int* in_sizes, int n_in,
                              void* d_out, int out_size, void* d_ws, size_t ws_size,
                              hipStream_t stream) {
    (void)in_sizes; (void)n_in; (void)out_size; (void)ws_size;
    const float* X   = (const float*)d_in[0];
    const float* adj = (const float*)d_in[1];
    const float* W0  = (const float*)d_in[2];
    const float* b0  = (const float*)d_in[3];
    const float* W1  = (const float*)d_in[4];
    const float* b1  = (const float*)d_in[5];
    const float* W2  = (const float*)d_in[6];
    const float* b2  = (const float*)d_in[7];
    float* out = (float*)d_out;

    // workspace layout (bf16): adjB | bufH (X/h, node-major) | tmpT (feat-major) | Wt x3
    char* ws = (char*)d_ws;
    const size_t SZ = 16777216;  // 32*512*512*2
    unsigned short* adjB = (unsigned short*)(ws);
    unsigned short* bufH = (unsigned short*)(ws + SZ);
    unsigned short* tmpT = (unsigned short*)(ws + 2 * SZ);
    unsigned short* Wt   = (unsigned short*)(ws + 3 * SZ);
    const unsigned short* W0t = Wt;
    const unsigned short* W1t = Wt + 262144;
    const unsigned short* W2t = Wt + 2 * 262144;

    prep_kernel<<<16384 + 768, 256, 0, stream>>>(X, adj, W0, W1, W2, bufH, adjB, Wt);

    const long BATCH = 512L * 512L;

    // layer 0: tmpT[e][node] = (h @ W0);  h = relu(adj @ tmp + b0) node-major
    gemm_abT_ct<512, 512, 16384, false, false, false, unsigned short>
        <<<512, 256, 0, stream>>>(bufH, W0t, tmpT, nullptr, 0, 0, 0);
    gemm_abT_ct<16384, 512, 512, true, true, true, unsigned short>
        <<<512, 256, 0, stream>>>(tmpT, adjB, bufH, b0, 512, BATCH, BATCH);
    // layer 1
    gemm_abT_ct<512, 512, 16384, false, false, false, unsigned short>
        <<<512, 256, 0, stream>>>(bufH, W1t, tmpT, nullptr, 0, 0, 0);
    gemm_abT_ct<16384, 512, 512, true, true, true, unsigned short>
        <<<512, 256, 0, stream>>>(tmpT, adjB, bufH, b1, 512, BATCH, BATCH);
    // layer 2 (no relu, fp32 out)
    gemm_abT_ct<512, 512, 16384, false, false, false, unsigned short>
        <<<512, 256, 0, stream>>>(bufH, W2t, tmpT, nullptr, 0, 0, 0);
    gemm_abT_ct<16384, 512, 512, true, false, true, float>
        <<<512, 256, 0, stream>>>(tmpT, adjB, out, b2, 512, BATCH, BATCH);
}

// Round 11
// 197.669 us; speedup vs baseline: 1.0602x; 1.0602x over previous
//
#include <hip/hip_runtime.h>
#include <stdint.h>

// ---------- types ----------
typedef __bf16 bf16x8 __attribute__((ext_vector_type(8)));
typedef float f32x4 __attribute__((ext_vector_type(4)));
typedef unsigned short u16x4 __attribute__((ext_vector_type(4)));

static __device__ __forceinline__ unsigned short f2bf(float f) {
    union { float f; unsigned u; } v; v.f = f;
    unsigned r = (v.u + 0x7FFFu + ((v.u >> 16) & 1u)) >> 16;  // RNE
    return (unsigned short)r;
}

// ---------- fused prep: convert X, convert adj, transpose W0/W1/W2 ----------
// Grid-strided convert (2048 blocks x 8 chunks) to cut dispatch overhead of
// 16384 tiny blocks (Guideline 11); W-transpose tiles unchanged.
__global__ void prep_kernel(const float* __restrict__ X,
                            const float* __restrict__ adj,
                            const float* __restrict__ W0,
                            const float* __restrict__ W1,
                            const float* __restrict__ W2,
                            unsigned short* __restrict__ bufH,
                            unsigned short* __restrict__ adjB,
                            unsigned short* __restrict__ Wt) {
    const int bid = blockIdx.x;
    const int t = threadIdx.x;
    if (bid < 2048) {
        #pragma unroll
        for (int s = 0; s < 8; ++s) {
            const int v = bid + s * 2048;           // virtual chunk 0..16383
            const float* src = (v < 8192) ? X : adj;
            unsigned short* dst = (v < 8192) ? bufH : adjB;
            const int i = (v & 8191) * 256 + t;
            f32x4 w = ((const f32x4*)src)[i];
            u16x4 o;
            o.x = f2bf(w.x); o.y = f2bf(w.y); o.z = f2bf(w.z); o.w = f2bf(w.w);
            ((u16x4*)dst)[i] = o;
        }
    } else {
        const int wb = bid - 2048;           // 0..767
        const int z = wb >> 8;               // which W
        const int tile = wb & 255;           // 16x16 tiles of 32x32
        const float* W = (z == 0) ? W0 : (z == 1) ? W1 : W2;
        unsigned short* out = Wt + (size_t)z * (512 * 512);
        __shared__ float tileS[32][33];
        const int bx = (tile & 15) * 32, by = (tile >> 4) * 32;
        const int tx = t & 31, ty = t >> 5;  // 32 x 8
        #pragma unroll
        for (int r = 0; r < 32; r += 8)
            tileS[ty + r][tx] = W[(size_t)(by + ty + r) * 512 + (bx + tx)];
        __syncthreads();
        #pragma unroll
        for (int r = 0; r < 32; r += 8)
            out[(size_t)(bx + ty + r) * 512 + (by + tx)] = f2bf(tileS[tx][ty + r]);
    }
}

// ---------- GEMM: D[m][n] = sum_k A[m*LDA+k]*B[n*LDB+k]; writes out[n*LDO+m]
// ROUND-5 BEST STRUCTURE (restored): 128x128 tile, BK=64 double-buffered,
// counted-vmcnt pipeline, XCD-affinity decode, coalesced LDS-transpose
// epilogue. This is the measured optimum across 10 structural variants
// (schedule/depth/occupancy/tile/affinity all null or regressions).
template<int LDA, int LDB, int LDO, bool BIAS, bool RELU, bool ADJ, typename OT>
__global__ __launch_bounds__(256, 2)
void gemm_abT_ct(const unsigned short* __restrict__ A,
                 const unsigned short* __restrict__ B,
                 OT* __restrict__ out, const float* __restrict__ bias,
                 long batchA, long batchB, long batchO) {
    __shared__ char SMEM[65536];
    unsigned short (*As)[8192] = (unsigned short (*)[8192])SMEM;            // 2 x 16 KB
    unsigned short (*Bs)[8192] = (unsigned short (*)[8192])(SMEM + 32768);  // 2 x 16 KB

    const int tid  = threadIdx.x;
    const int lane = tid & 63;
    const int wave = tid >> 6;
    const int quad = lane >> 4;
    const int l16  = lane & 15;
    const int wm   = wave & 1;
    const int wn   = wave >> 1;

    // ---- XCD-affinity decode (bijective over 512 blocks) ----
    const int L = blockIdx.x;
    const int x = L & 7;        // XCD id (hw round-robin on linear block id)
    const int j = L >> 3;       // 0..63 within XCD
    int m0, n0;
    long z;
    if constexpr (ADJ) {
        z = x + 8 * (j >> 4);             // 4 z's per XCD
        const int t4 = j & 15;            // 16 tiles of this z
        m0 = (t4 & 3) * 128;
        n0 = (t4 >> 2) * 128;
    } else {
        z = 0;
        m0 = (x * 16 + (j >> 2)) * 128;   // XCD x owns 16 consecutive m-tiles
        n0 = (j & 3) * 128;
    }
    A   += (size_t)z * batchA;
    B   += (size_t)z * batchB;
    out += (size_t)z * batchO;

    const int trow8 = tid >> 3;                   // 0..31
    const int tpos8 = (tid & 7) ^ (trow8 & 7);    // r-independent swizzled pos
    const unsigned short* aG = A + (size_t)(m0 + trow8) * LDA + tpos8 * 8;
    const unsigned short* bG = B + (size_t)(n0 + trow8) * LDB + tpos8 * 8;

    f32x4 acc[4][4];
    #pragma unroll
    for (int i = 0; i < 4; ++i)
        #pragma unroll
        for (int j2 = 0; j2 < 4; ++j2) {
            f32x4 zz = {0.f, 0.f, 0.f, 0.f};
            acc[i][j2] = zz;
        }

#define STAGE(buf, ko)                                                         \
    do {                                                                       \
        char* aL = (char*)(As[buf]) + tid * 16;                                \
        char* bL = (char*)(Bs[buf]) + tid * 16;                                \
        _Pragma("unroll")                                                      \
        for (int r = 0; r < 4; ++r)                                            \
            __builtin_amdgcn_global_load_lds(                                  \
                (__attribute__((address_space(1))) void*)(uintptr_t)(aG + (size_t)(r * 32) * LDA + (ko)), \
                (__attribute__((address_space(3))) void*)(aL + r * 4096), 16, 0, 0); \
        _Pragma("unroll")                                                      \
        for (int r = 0; r < 4; ++r)                                            \
            __builtin_amdgcn_global_load_lds(                                  \
                (__attribute__((address_space(1))) void*)(uintptr_t)(bG + (size_t)(r * 32) * LDB + (ko)), \
                (__attribute__((address_space(3))) void*)(bL + r * 4096), 16, 0, 0); \
    } while (0)

#define COMPUTE(buf)                                                           \
    do {                                                                       \
        _Pragma("unroll")                                                      \
        for (int ks = 0; ks < 2; ++ks) {                                       \
            bf16x8 af[4], bfr[4];                                              \
            _Pragma("unroll")                                                  \
            for (int i = 0; i < 4; ++i) {                                      \
                const int row = wm * 64 + i * 16 + l16;                        \
                const int idx = row * 8 + ((ks * 4 + quad) ^ (row & 7));       \
                af[i] = *(const bf16x8*)((const char*)(As[buf]) + idx * 16);   \
            }                                                                  \
            _Pragma("unroll")                                                  \
            for (int j2 = 0; j2 < 4; ++j2) {                                   \
                const int row = wn * 64 + j2 * 16 + l16;                       \
                const int idx = row * 8 + ((ks * 4 + quad) ^ (row & 7));       \
                bfr[j2] = *(const bf16x8*)((const char*)(Bs[buf]) + idx * 16); \
            }                                                                  \
            _Pragma("unroll")                                                  \
            for (int i = 0; i < 4; ++i)                                        \
                _Pragma("unroll")                                              \
                for (int j2 = 0; j2 < 4; ++j2)                                 \
                    acc[i][j2] = __builtin_amdgcn_mfma_f32_16x16x32_bf16(af[i], bfr[j2], acc[i][j2], 0, 0, 0); \
        }                                                                      \
    } while (0)

    STAGE(0, 0);     // -> buf0
    STAGE(1, 64);    // -> buf1   (16 loads in flight)

    #pragma unroll 1
    for (int kp = 0; kp < 4; ++kp) {       // K = 512 = 4 x (two 64-halves)
        const int ko = kp * 128;
        // ---- half A: buf0 (k = ko) ----
        asm volatile("s_waitcnt vmcnt(8)" ::: "memory");   // my buf0 loads done
        __builtin_amdgcn_s_barrier();                      // all waves ready
        __builtin_amdgcn_s_setprio(1);
        COMPUTE(0);
        __builtin_amdgcn_s_setprio(0);
        asm volatile("s_waitcnt lgkmcnt(0)" ::: "memory"); // my ds_reads of buf0 done
        __builtin_amdgcn_sched_barrier(0);
        __builtin_amdgcn_s_barrier();                      // all waves done reading buf0
        if (kp < 3) STAGE(0, ko + 128);                    // refill buf0
        // ---- half B: buf1 (k = ko + 64) ----
        if (kp < 3) asm volatile("s_waitcnt vmcnt(8)" ::: "memory");
        else        asm volatile("s_waitcnt vmcnt(0)" ::: "memory");
        __builtin_amdgcn_s_barrier();
        __builtin_amdgcn_s_setprio(1);
        COMPUTE(1);
        __builtin_amdgcn_s_setprio(0);
        asm volatile("s_waitcnt lgkmcnt(0)" ::: "memory");
        __builtin_amdgcn_sched_barrier(0);
        __builtin_amdgcn_s_barrier();
        if (kp < 3) STAGE(1, ko + 192);
    }
#undef STAGE
#undef COMPUTE

    // ---- coalesced epilogue via LDS transpose ----
    if constexpr (sizeof(OT) == 2) {
        // bf16 tile [n=128][m=128], 256B rows = 16 x 16B chunks, chunk ^= n&7
        unsigned short* T = (unsigned short*)SMEM;   // 32 KB
        #pragma unroll
        for (int i = 0; i < 4; ++i) {
            const int mloc = wm * 64 + i * 16 + quad * 4;
            const int mb = m0 + mloc;
            f32x4 bb = {0.f, 0.f, 0.f, 0.f};
            if constexpr (BIAS) bb = *(const f32x4*)(bias + mb);
            const int ch  = mloc >> 3;           // 16B chunk index 0..15
            const int sub = (mloc & 7) * 2;      // byte offset within chunk
            #pragma unroll
            for (int j2 = 0; j2 < 4; ++j2) {
                const int nloc = wn * 64 + j2 * 16 + l16;
                f32x4 v = acc[i][j2];
                if constexpr (BIAS) v += bb;
                if constexpr (RELU) {
                    v.x = v.x > 0.f ? v.x : 0.f;
                    v.y = v.y > 0.f ? v.y : 0.f;
                    v.z = v.z > 0.f ? v.z : 0.f;
                    v.w = v.w > 0.f ? v.w : 0.f;
                }
                u16x4 o;
                o.x = f2bf(v.x); o.y = f2bf(v.y); o.z = f2bf(v.z); o.w = f2bf(v.w);
                *(u16x4*)((char*)T + nloc * 256 + ((ch ^ (nloc & 7)) << 4) + sub) = o;
            }
        }
        __syncthreads();
        #pragma unroll
        for (int it = 0; it < 8; ++it) {
            const int n  = (tid >> 4) + 16 * it;   // 0..127
            const int cc = tid & 15;               // 16 lanes = 256B dense row
            f32x4 d = *(const f32x4*)((const char*)T + n * 256 + ((cc ^ (n & 7)) << 4));
            *(f32x4*)((unsigned short*)out + (size_t)(n0 + n) * LDO + m0 + cc * 8) = d;
        }
    } else {
        // f32 tile [n=128][m=128], 512B rows = 32 x 16B chunks, chunk ^= n&7 (64 KB)
        float* T = (float*)SMEM;
        #pragma unroll
        for (int i = 0; i < 4; ++i) {
            const int mloc = wm * 64 + i * 16 + quad * 4;
            const int mb = m0 + mloc;
            f32x4 bb = {0.f, 0.f, 0.f, 0.f};
            if constexpr (BIAS) bb = *(const f32x4*)(bias + mb);
            const int ch = mloc >> 2;            // 16B chunk index 0..31
            #pragma unroll
            for (int j2 = 0; j2 < 4; ++j2) {
                const int nloc = wn * 64 + j2 * 16 + l16;
                f32x4 v = acc[i][j2];
                if constexpr (BIAS) v += bb;
                if constexpr (RELU) {
                    v.x = v.x > 0.f ? v.x : 0.f;
                    v.y = v.y > 0.f ? v.y : 0.f;
                    v.z = v.z > 0.f ? v.z : 0.f;
                    v.w = v.w > 0.f ? v.w : 0.f;
                }
                *(f32x4*)((char*)T + nloc * 512 + ((ch ^ (nloc & 7)) << 4)) = v;
            }
        }
        __syncthreads();
        #pragma unroll
        for (int it = 0; it < 16; ++it) {
            const int n  = (tid >> 4) + 16 * (it >> 1);      // 0..127
            const int cc = (tid & 15) + 16 * (it & 1);       // 0..31
            f32x4 d = *(const f32x4*)((const char*)T + n * 512 + ((cc ^ (n & 7)) << 4));
            *(f32x4*)((float*)out + (size_t)(n0 + n) * LDO + m0 + cc * 4) = d;
        }
    }
}

extern "C" void kernel_launch(void* const* d_in, const int* in_sizes, int n_in,
                              void* d_out, int out_size, void* d_ws, size_t ws_size,
                              hipStream_t stream) {
    (void)in_sizes; (void)n_in; (void)out_size; (void)ws_size;
    const float* X   = (const float*)d_in[0];
    const float* adj = (const float*)d_in[1];
    const float* W0  = (const float*)d_in[2];
    const float* b0  = (const float*)d_in[3];
    const float* W1  = (const float*)d_in[4];
    const float* b1  = (const float*)d_in[5];
    const float* W2  = (const float*)d_in[6];
    const float* b2  = (const float*)d_in[7];
    float* out = (float*)d_out;

    // workspace layout (bf16): adjB | bufH (X/h, node-major) | tmpT (feat-major) | Wt x3
    char* ws = (char*)d_ws;
    const size_t SZ = 16777216;  // 32*512*512*2
    unsigned short* adjB = (unsigned short*)(ws);
    unsigned short* bufH = (unsigned short*)(ws + SZ);
    unsigned short* tmpT = (unsigned short*)(ws + 2 * SZ);
    unsigned short* Wt   = (unsigned short*)(ws + 3 * SZ);
    const unsigned short* W0t = Wt;
    const unsigned short* W1t = Wt + 262144;
    const unsigned short* W2t = Wt + 2 * 262144;

    prep_kernel<<<2048 + 768, 256, 0, stream>>>(X, adj, W0, W1, W2, bufH, adjB, Wt);

    const long BATCH = 512L * 512L;

    // layer 0: tmpT[e][node] = (h @ W0);  h = relu(adj @ tmp + b0) node-major
    gemm_abT_ct<512, 512, 16384, false, false, false, unsigned short>
        <<<512, 256, 0, stream>>>(bufH, W0t, tmpT, nullptr, 0, 0, 0);
    gemm_abT_ct<16384, 512, 512, true, true, true, unsigned short>
        <<<512, 256, 0, stream>>>(tmpT, adjB, bufH, b0, 512, BATCH, BATCH);
    // layer 1
    gemm_abT_ct<512, 512, 16384, false, false, false, unsigned short>
        <<<512, 256, 0, stream>>>(bufH, W1t, tmpT, nullptr, 0, 0, 0);
    gemm_abT_ct<16384, 512, 512, true, true, true, unsigned short>
        <<<512, 256, 0, stream>>>(tmpT, adjB, bufH, b1, 512, BATCH, BATCH);
    // layer 2 (no relu, fp32 out)
    gemm_abT_ct<512, 512, 16384, false, false, false, unsigned short>
        <<<512, 256, 0, stream>>>(bufH, W2t, tmpT, nullptr, 0, 0, 0);
    gemm_abT_ct<16384, 512, 512, true, false, true, float>
        <<<512, 256, 0, stream>>>(tmpT, adjB, out, b2, 512, BATCH, BATCH);
}